// Round 1
// 167.667 us; speedup vs baseline: 1.0112x; 1.0112x over previous
//
#include <hip/hip_runtime.h>

// STKBranch double-softmax attention, f16-MFMA 2-pass, R12:
//   - SWAPPED QK^T (C = K x Q^T): lane holds S[key=q4*4+r][q=l15], which is
//     exactly the B-fragment of mfma_f32_16x16x16_f16 -> PV consumes P directly
//     from registers. Ps LDS tile DELETED (was the only bank-conflicting access
//     + a serial write->lgkm->read chain per tile).
//   - Q fragments loaded straight from global (per-lane contiguous 32B x2),
//     Qs LDS + its barrier DELETED. LDS 73728 -> 36864 B.
//   - PV: O^T[d][q] += V^T x P^T via 16x16x16 MFMA; A = V^T fragments are
//     ds_read_b64 from Vt[d][key] (bank-balanced, floor).
//   - s1/l2 reductions now 1 scalar x 2 shuffles (xor 16,32); output float4.
//   - keeps R10/R11 pipeline: Ks/Vt double-buffered, reg prefetch kt+2,
//     1 barrier/tile, scale*2*log2e folded into Q fragments.
// Math: L = scale*q@k^T ; w = softmax(2L) ; attn = softmax(L*w) ; out = attn@v
// |L| <= ~7 -> no max-subtraction. B=4 H=8 N=2048 D=64 fp32 io.

typedef _Float16 f16;
typedef f16 f16x8 __attribute__((ext_vector_type(8)));
typedef f16 f16x4 __attribute__((ext_vector_type(4)));
typedef float f32x4 __attribute__((ext_vector_type(4)));

#define MFMA32(a, b, c) __builtin_amdgcn_mfma_f32_16x16x32_f16((a), (b), (c), 0, 0, 0)
#define MFMA16(a, b, c) __builtin_amdgcn_mfma_f32_16x16x16f16((a), (b), (c), 0, 0, 0)
#define EXP2(x) __builtin_amdgcn_exp2f(x)   // v_exp_f32: D = 2^S0

#define N_CTX 2048
#define DH 64
#define KT 64
#define NKT (N_CTX / KT)
#define ROWS 128          // 8 waves x 16 q-rows
#define QS 72             // universal LDS row stride (f16): 144 B

#define C2 2.885390081777927f    // 2*log2(e), folded into Q fragments

__device__ inline unsigned pk(float a, float b) {
    typedef __fp16 fp16x2_t __attribute__((ext_vector_type(2)));
    union { fp16x2_t v; unsigned u; } x;
    x.v = __builtin_amdgcn_cvt_pkrtz(a, b);
    return x.u;
}

__global__ __launch_bounds__(512, 4)
void stk_attn_mfma(const float* __restrict__ qg, const float* __restrict__ kg,
                   const float* __restrict__ vglob, const float* __restrict__ sg,
                   float* __restrict__ og) {
    __shared__ f16 Ks[2][KT * QS];      // 18432 B (double-buffered), [key][d]
    __shared__ f16 Vt[2][DH * QS];      // 18432 B (double-buffered), [d][key]
                                        // total 36864 B

    const int tid  = threadIdx.x;
    const int wv   = tid >> 6;        // 0..7
    const int lane = tid & 63;
    const int l15  = lane & 15;
    const int q4   = lane >> 4;
    const int vp   = tid & 31;        // V staging: key pair (2vp, 2vp+1)
    const int vgr  = tid >> 5;        // V staging: d-quad (0..15 -> d = vgr*4..+3)
    const int bh   = blockIdx.x & 31; // XCD swizzle: head h -> blocks h+32j -> XCD h%8
    const int q0   = (blockIdx.x >> 5) * ROWS;
    const float scale2 = sg[0] * C2;  // fold 2*log2e: acc = 2L*log2e

    const float* qb = qg + (size_t)bh * N_CTX * DH;
    const float* kb = kg + (size_t)bh * N_CTX * DH;
    const float* vb = vglob + (size_t)bh * N_CTX * DH;
    float*       ob = og + (size_t)bh * N_CTX * DH;

    // ---- Q fragments direct from global (no LDS): row wv*16+l15, d = kc*32+q4*8.. ----
    // Used as the B operand of the swapped QK^T: B[k=q4*8+e][col=l15] = Q[l15-row][k]*scale2.
    f16x8 aq[2];
    {
        const float* qrow = qb + (size_t)(q0 + wv * 16 + l15) * DH;
        #pragma unroll
        for (int kc = 0; kc < 2; ++kc) {
            float4 a0 = *(const float4*)&qrow[kc * 32 + q4 * 8];
            float4 a1 = *(const float4*)&qrow[kc * 32 + q4 * 8 + 4];
            union { f16x8 h; unsigned u[4]; } A;
            A.u[0] = pk(a0.x * scale2, a0.y * scale2);
            A.u[1] = pk(a0.z * scale2, a0.w * scale2);
            A.u[2] = pk(a1.x * scale2, a1.y * scale2);
            A.u[3] = pk(a1.z * scale2, a1.w * scale2);
            aq[kc] = A.h;
        }
    }

    // loop-invariant LDS lane bases (all ds offsets below are immediates)
    f16* const ks_w  = &Ks[0][0];                    // + staging idx
    const f16* const ks_r = &Ks[0][l15 * QS + q4 * 8];   // A-frag of QK^T: K row l15
    f16* const vt_w  = &Vt[0][(vgr * 4) * QS + 2 * vp];
    const f16* const vt_r = &Vt[0][l15 * QS + q4 * 4];   // A-frag of PV: V^T row l15, keys q4*4..
    const int KSB = KT * QS;                         // Ks/Vt buffer stride (f16)

    // =============== PASS 1: s1 = sum_k exp(2L) per q-row ===============
    float s1 = 0.f;
    float4 kr[2];
    #pragma unroll
    for (int it = 0; it < 2; ++it) {
        int idx = it * 512 + tid;
        kr[it] = *(const float4*)&kb[((size_t)(idx >> 4)) * DH + (idx & 15) * 4];
    }
    #pragma unroll
    for (int it = 0; it < 2; ++it) {
        int idx = it * 512 + tid;
        *(uint2*)&ks_w[(idx >> 4) * QS + (idx & 15) * 4] =
            make_uint2(pk(kr[it].x, kr[it].y), pk(kr[it].z, kr[it].w));
    }
    #pragma unroll
    for (int it = 0; it < 2; ++it) {
        int idx = it * 512 + tid;
        kr[it] = *(const float4*)&kb[((size_t)KT + (idx >> 4)) * DH + (idx & 15) * 4];
    }
    __syncthreads();

    for (int kt = 0; kt < NKT; ++kt) {
        const int cur = (kt & 1) * KSB, nxt = KSB - cur;
        #pragma unroll
        for (int it = 0; it < 2; ++it) {
            int idx = it * 512 + tid;
            *(uint2*)&ks_w[nxt + (idx >> 4) * QS + (idx & 15) * 4] =
                make_uint2(pk(kr[it].x, kr[it].y), pk(kr[it].z, kr[it].w));
        }
        {
            int tn = (kt + 2 < NKT) ? kt + 2 : NKT - 1;
            #pragma unroll
            for (int it = 0; it < 2; ++it) {
                int idx = it * 512 + tid;
                kr[it] = *(const float4*)&kb[((size_t)tn * KT + (idx >> 4)) * DH + (idx & 15) * 4];
            }
        }
        #pragma unroll
        for (int kgi = 0; kgi < 4; ++kgi) {
            f16x8 b0 = *(const f16x8*)&ks_r[cur + kgi * 16 * QS];
            f16x8 b1 = *(const f16x8*)&ks_r[cur + kgi * 16 * QS + 32];
            f32x4 acc = {0.f, 0.f, 0.f, 0.f};
            acc = MFMA32(b0, aq[0], acc);   // swapped: C[key][q], lane q = l15
            acc = MFMA32(b1, aq[1], acc);
            s1 += EXP2(acc[0]);
            s1 += EXP2(acc[1]);
            s1 += EXP2(acc[2]);
            s1 += EXP2(acc[3]);
        }
        __syncthreads();
    }
    // reduce across q4 groups (key partitions): lanes l15, l15+16, l15+32, l15+48
    s1 += __shfl_xor(s1, 16, 64);
    s1 += __shfl_xor(s1, 32, 64);
    const float inv1 = 0.5f / s1;    // e2 = exp2((acc*e1) * 0.5/s1)  [acc = 2L*log2e]

    // =============== PASS 2: e2, O^T += V^T P^T ===============
    float l2 = 0.f;
    f32x4 O[4];
    #pragma unroll
    for (int dt = 0; dt < 4; ++dt) O[dt] = (f32x4){0.f, 0.f, 0.f, 0.f};

    float4 vr[2];
    // prologue: Ks[0]<-K(0), Vt[0]<-V(0); kr<-K(1), vr<-V(1)
    #pragma unroll
    for (int it = 0; it < 2; ++it) {
        int idx = it * 512 + tid;
        kr[it] = *(const float4*)&kb[((size_t)(idx >> 4)) * DH + (idx & 15) * 4];
    }
    #pragma unroll
    for (int it = 0; it < 2; ++it) {
        int idx = it * 512 + tid;
        *(uint2*)&ks_w[(idx >> 4) * QS + (idx & 15) * 4] =
            make_uint2(pk(kr[it].x, kr[it].y), pk(kr[it].z, kr[it].w));
    }
    {
        const float* vs = vb + ((size_t)2 * vp) * DH + vgr * 4;
        vr[0] = *(const float4*)(vs);
        vr[1] = *(const float4*)(vs + DH);
        #pragma unroll
        for (int j = 0; j < 4; ++j)
            *(unsigned*)&vt_w[j * QS] =
                pk(((const float*)&vr[0])[j], ((const float*)&vr[1])[j]);
        const float* vs1 = vb + ((size_t)KT + 2 * vp) * DH + vgr * 4;
        vr[0] = *(const float4*)(vs1);
        vr[1] = *(const float4*)(vs1 + DH);
    }
    #pragma unroll
    for (int it = 0; it < 2; ++it) {
        int idx = it * 512 + tid;
        kr[it] = *(const float4*)&kb[((size_t)KT + (idx >> 4)) * DH + (idx & 15) * 4];
    }
    __syncthreads();

    for (int kt = 0; kt < NKT; ++kt) {
        const int cur = (kt & 1) * KSB, nxt = KSB - cur;
        // stage next K/V tile into the other buffers (overlaps all compute below)
        #pragma unroll
        for (int it = 0; it < 2; ++it) {
            int idx = it * 512 + tid;
            *(uint2*)&ks_w[nxt + (idx >> 4) * QS + (idx & 15) * 4] =
                make_uint2(pk(kr[it].x, kr[it].y), pk(kr[it].z, kr[it].w));
        }
        #pragma unroll
        for (int j = 0; j < 4; ++j)
            *(unsigned*)&vt_w[nxt + j * QS] =
                pk(((const float*)&vr[0])[j], ((const float*)&vr[1])[j]);
        // QK^T (swapped) on Ks[cur] + softmax chain; P stays in registers as
        // the ready-made B-fragment of the 16x16x16 PV MFMA.
        f16x4 pfr[4];
        #pragma unroll
        for (int kgi = 0; kgi < 4; ++kgi) {
            f16x8 b0 = *(const f16x8*)&ks_r[cur + kgi * 16 * QS];
            f16x8 b1 = *(const f16x8*)&ks_r[cur + kgi * 16 * QS + 32];
            f32x4 acc = {0.f, 0.f, 0.f, 0.f};
            acc = MFMA32(b0, aq[0], acc);
            acc = MFMA32(b1, aq[1], acc);
            float e2r[4];
            #pragma unroll
            for (int r = 0; r < 4; ++r) {
                float a  = acc[r];
                float e1 = EXP2(a);
                float e2 = EXP2((a * e1) * inv1);
                l2 += e2;
                e2r[r] = e2;
            }
            union { f16x4 h; unsigned u[2]; } P;
            P.u[0] = pk(e2r[0], e2r[1]);
            P.u[1] = pk(e2r[2], e2r[3]);
            pfr[kgi] = P.h;
        }
        // prefetch K(kt+2), V(kt+2) (clamped; loads in flight during PV)
        {
            int tn = (kt + 2 < NKT) ? kt + 2 : NKT - 1;
            #pragma unroll
            for (int it = 0; it < 2; ++it) {
                int idx = it * 512 + tid;
                kr[it] = *(const float4*)&kb[((size_t)tn * KT + (idx >> 4)) * DH + (idx & 15) * 4];
            }
            const float* vs = vb + ((size_t)tn * KT + 2 * vp) * DH + vgr * 4;
            vr[0] = *(const float4*)(vs);
            vr[1] = *(const float4*)(vs + DH);
        }
        // PV: O^T[d][q] += sum_key V^T[d][key] * P^T[key][q], 16x16x16 MFMA,
        // A-fragment = 4 consecutive keys of V^T row (dt*16+l15) -> ds_read_b64.
        #pragma unroll
        for (int kgi = 0; kgi < 4; ++kgi) {
            #pragma unroll
            for (int dt = 0; dt < 4; ++dt) {
                f16x4 av = *(const f16x4*)&vt_r[cur + dt * 16 * QS + kgi * 16];
                O[dt] = MFMA16(av, pfr[kgi], O[dt]);
            }
        }
        __syncthreads();   // swap: protects Ks/Vt cur<->nxt for next iteration
    }

    // ---- finalize: lane holds O^T[d = dt*16+q4*4+r][q = wv*16+l15] ----
    l2 += __shfl_xor(l2, 16, 64);
    l2 += __shfl_xor(l2, 32, 64);
    const float invl2 = 1.0f / l2;
    const size_t orow = (size_t)(q0 + wv * 16 + l15) * DH;
    #pragma unroll
    for (int dt = 0; dt < 4; ++dt) {
        float4 o;
        o.x = O[dt][0] * invl2;
        o.y = O[dt][1] * invl2;
        o.z = O[dt][2] * invl2;
        o.w = O[dt][3] * invl2;
        *(float4*)&ob[orow + dt * 16 + q4 * 4] = o;
    }
}

extern "C" void kernel_launch(void* const* d_in, const int* in_sizes, int n_in,
                              void* d_out, int out_size, void* d_ws, size_t ws_size,
                              hipStream_t stream) {
    const float* q = (const float*)d_in[0];
    const float* k = (const float*)d_in[1];
    const float* v = (const float*)d_in[2];
    const float* s = (const float*)d_in[3];
    float* out = (float*)d_out;
    dim3 grid(32 * 16);   // bh = blockIdx&31 (XCD swizzle), q-tile = blockIdx>>5
    stk_attn_mfma<<<grid, 512, 0, stream>>>(q, k, v, s, out);
}